// Round 3
// baseline (250.239 us; speedup 1.0000x reference)
//
#include <hip/hip_runtime.h>

typedef unsigned short u16;
typedef unsigned int u32;
typedef __attribute__((ext_vector_type(8))) short bf16x8;
typedef __attribute__((ext_vector_type(4))) float f32x4;

#define B_TOT 16384
#define RPW 16               // batch rows per wave (= per block)
#define BLK 64               // 1 wave per block: all sync is in-wave
#define NBLK (B_TOT / RPW)   // 1024 blocks -> 4 waves/CU (1 per SIMD)
#define TT 30
#define LL 100
#define DTC 0.03f
#define L2E 1.44269504088896f

#define HST 104              // u16 stride of H rows (h 0..63, x 64..67, bias 68, pad..103)

// ---- LDS byte offsets (per 1-wave block), total 13568 ----
#define OFF_HS  0            // u16[16][104] = 3328  : LSTM state / lv-MLP chain
#define OFF_XS  3328         // u16[16][64]  = 2048  : mean-MLP chain scratch
#define OFF_INP 5376         // u16[16][120] = 3840  : encoder inputs (bf16)
#define OFF_ZB  9216         // u16[16][136] = 4352  : z, zero-padded to K=128
#define SMEM_SZ 13568

// ---- d_ws u16 offsets (unchanged from proven baseline) ----
#define WS_WHHE  0        // [256][72]: cols0-63 whh*scale, 64-67 fold, 68 bias, 69-71 zero
#define WS_WHHD  18432
#define WS_MWS   36864    // mean_Ws 3x[64][64]
#define WS_LWS   49152
#define WS_MWF   61440    // [100][64]
#define WS_LWF   67840
#define WS_WINIT 74240    // [64][128] zero-padded
#define WS_TOTAL 82432

__device__ __forceinline__ float bf2f(u16 u) {
    union { u32 i; float f; } v; v.i = ((u32)u) << 16; return v.f;
}
__device__ __forceinline__ u16 f2bf(float f) {          // RNE (setup / one-shot paths)
    union { float f; u32 i; } v; v.f = f;
    return (u16)((v.i + 0x7FFFu + ((v.i >> 16) & 1u)) >> 16);
}
__device__ __forceinline__ u16 f2bf_t(float f) {        // truncation (hot paths)
    union { float f; u32 i; } v; v.f = f;
    return (u16)(v.i >> 16);
}
__device__ __forceinline__ float rcpf(float x) { return __builtin_amdgcn_rcpf(x); }
__device__ __forceinline__ float ex2(float x) { return __builtin_amdgcn_exp2f(x); }
__device__ __forceinline__ float tanh_(float x) {
    x = fminf(fmaxf(x, -15.f), 15.f);
    float e = __expf(2.f * x);
    return (e - 1.f) * rcpf(e + 1.f);
}
__device__ __forceinline__ float leaky(float x) { return x >= 0.f ? x : 0.01f * x; }
__device__ __forceinline__ f32x4 mfma16(bf16x8 a, bf16x8 b, f32x4 c) {
    return __builtin_amdgcn_mfma_f32_16x16x32_bf16(a, b, c, 0, 0, 0);
}

// ================= setup kernel: weight prep into d_ws (unchanged) =================
__global__ void setup_kernel(
    const float* __restrict__ W_se, const float* __restrict__ b_se,
    const float* __restrict__ W_ih_e, const float* __restrict__ W_hh_e,
    const float* __restrict__ b_ih_e, const float* __restrict__ b_hh_e,
    const float* __restrict__ W_ih_d, const float* __restrict__ W_hh_d,
    const float* __restrict__ b_ih_d, const float* __restrict__ b_hh_d,
    const float* __restrict__ mean_Ws, const float* __restrict__ lv_Ws,
    const float* __restrict__ mean_Wf, const float* __restrict__ lv_Wf,
    const float* __restrict__ W_init, u16* __restrict__ ws)
{
    const int gid = blockIdx.x * 256 + threadIdx.x;
    const int nth = gridDim.x * 256;
    // A: folded input-proj tails (512 dot-tasks)
    for (int i = gid; i < 512; i += nth) {
        int which = i >> 8, row = i & 255, g = row >> 6;
        float s = (g == 2) ? 2.f * L2E : L2E;
        const float* wih = (which ? W_ih_d : W_ih_e) + row * 64;
        float f0=0,f1=0,f2=0,f3=0,fb=0;
        for (int e = 0; e < 64; ++e) {
            float w = wih[e];
            f0 = fmaf(w, W_se[e*4+0], f0);
            f1 = fmaf(w, W_se[e*4+1], f1);
            f2 = fmaf(w, W_se[e*4+2], f2);
            f3 = fmaf(w, W_se[e*4+3], f3);
            fb = fmaf(w, b_se[e], fb);
        }
        fb += (which ? b_ih_d : b_ih_e)[row] + (which ? b_hh_d : b_hh_e)[row];
        u16* dst = ws + (which ? WS_WHHD : WS_WHHE) + row * 72 + 64;
        dst[0]=f2bf(f0*s); dst[1]=f2bf(f1*s); dst[2]=f2bf(f2*s); dst[3]=f2bf(f3*s);
        dst[4]=f2bf(fb*s); dst[5]=0; dst[6]=0; dst[7]=0;
    }
    // B: scaled W_hh rows
    for (int i = gid; i < 2*16384; i += nth) {
        int which = i >= 16384;
        int j = which ? i - 16384 : i;
        int row = j >> 6, k = j & 63, g = row >> 6;
        float s = (g == 2) ? 2.f * L2E : L2E;
        const float* whh = which ? W_hh_d : W_hh_e;
        ws[(which ? WS_WHHD : WS_WHHE) + row*72 + k] = f2bf(whh[j] * s);
    }
    // C: MLP hidden weights
    for (int i = gid; i < 12288; i += nth) {
        ws[WS_MWS + i] = f2bf(mean_Ws[i]);
        ws[WS_LWS + i] = f2bf(lv_Ws[i]);
    }
    // D: MLP final weights
    for (int i = gid; i < 6400; i += nth) {
        ws[WS_MWF + i] = f2bf(mean_Wf[i]);
        ws[WS_LWF + i] = f2bf(lv_Wf[i]);
    }
    // E: W_init zero-padded [64][128]
    for (int i = gid; i < 8192; i += nth) {
        int r = i >> 7, k = i & 127;
        ws[WS_WINIT + i] = (k < LL) ? f2bf(W_init[r*LL + k]) : (u16)0;
    }
}

// ================= main fused kernel: 1 wave owns 16 rows end-to-end =================
// No __syncthreads in any loop: producer==consumer (same wave). A wave's DS
// instructions execute in program order, so the MFMA D->A transpose round-trips
// through wave-private LDS with no barrier. B-fragments for all 4 gates x 4
// unit-tiles live in VGPRs (48 x bf16x8 = 192); launch_bounds(64,1) -> 512-reg budget.
__global__ __launch_bounds__(BLK, 1) void vae_lstm_kernel(
    const float* __restrict__ expert, const float* __restrict__ init_state,
    const float* __restrict__ eps, const u16* __restrict__ ws,
    const float* __restrict__ mean_bs, const float* __restrict__ mean_bf,
    const float* __restrict__ lv_bs, const float* __restrict__ lv_bf,
    const float* __restrict__ b_init, const float* __restrict__ W_c,
    const float* __restrict__ b_c,
    float* __restrict__ out_recons, float* __restrict__ out_expert,
    float* __restrict__ out_mu, float* __restrict__ out_lv)
{
    const int l = threadIdx.x;        // 0..63
    const int lcol = l & 15;
    const int quad = l >> 4;
    const int b0 = blockIdx.x * RPW;  // this wave's batch-row base

    __shared__ __align__(16) char smem[SMEM_SZ];
    u16* Hs  = (u16*)(smem + OFF_HS);
    u16* XS  = (u16*)(smem + OFF_XS);
    u16* inp = (u16*)(smem + OFF_INP);
    u16* zB  = (u16*)(smem + OFF_ZB);

    // ---- staging (wave-local, no barrier needed) ----
    {
        // FULL zero of Hs [16][52] u32 = 832 words. Critical: a2 reads cols 64..95;
        // any uninitialized NaN there would poison MFMA even against a zero B-frag.
        u32* hz = (u32*)Hs;
#pragma unroll
        for (int i = 0; i < 13; ++i) hz[l + i * 64] = 0;     // 832 u32 exactly
        if (l < RPW) Hs[l*HST + 68] = 0x3F80;   // bias column = 1.0 (after zeroing)
        // zero zB (pad cols >= 100 must be 0 for the K=128 W_init matmul)
        u32* zz = (u32*)zB;
#pragma unroll
        for (int i = 0; i < 17; ++i) zz[l + i * 64] = 0;     // 1088 u32 exactly
        // expert load + passthrough + rel-xy -> inp ; x(t=0) -> Hs
        const int base = b0 * (TT*4);
#pragma unroll 4
        for (int i = 0; i < 30; ++i) {
            int idx = l + i * 64;            // 0..1919
            int row = idx / 120, q = idx % 120;
            int t = q >> 2, k = q & 3;
            float v = expert[base + idx];
            out_expert[base + idx] = v;
            float r = v;
            if (k < 2 && t > 0) r = v - expert[base + idx - 4];
            u16 hv = f2bf(r);
            inp[row*120 + q] = hv;
            if (t == 0) Hs[row*HST + 64 + k] = hv;
        }
        __syncthreads();   // single-wave: compiles to a waitcnt; drains staging
    }

    float cst[4][4] = {};      // c-state: [unit-block u][row-reg r]
    float hval[4][4];          // f32 h of the current step (decoder ctrl input)
    bf16x8 bw[4][4][3];        // B-frags: [gate g][unit-block u][k-block]

    auto build_bw = [&](const u16* wsW) {
#pragma unroll
        for (int g = 0; g < 4; ++g)
#pragma unroll
            for (int u = 0; u < 4; ++u) {
                const u16* wr = wsW + (g*64 + u*16 + lcol) * 72;
                bw[g][u][0] = *(const bf16x8*)(wr + quad*8);
                bw[g][u][1] = *(const bf16x8*)(wr + 32 + quad*8);
                if (quad == 0) {
                    bw[g][u][2] = *(const bf16x8*)(wr + 64);
                } else {
                    bf16x8 z;
#pragma unroll
                    for (int j = 0; j < 8; ++j) z[j] = 0;
                    bw[g][u][2] = z;
                }
            }
    };

    // one LSTM step for this wave's 16 rows: 48 MFMA (K=96) + fused gate epilogue.
    // Reads rows (lcol) then writes rows (quad*4+r): same-wave DS ordering makes the
    // single-buffer read-then-write safe.
    auto lstm_step = [&]() {
        const u16* hrow = Hs + lcol*HST;
        bf16x8 a0 = *(const bf16x8*)(hrow + quad*8);
        bf16x8 a1 = *(const bf16x8*)(hrow + 32 + quad*8);
        bf16x8 a2 = *(const bf16x8*)(hrow + 64 + quad*8);
        f32x4 acc[4][4];
#pragma unroll
        for (int g = 0; g < 4; ++g)
#pragma unroll
            for (int u = 0; u < 4; ++u) {
                f32x4 z = {0.f, 0.f, 0.f, 0.f};
                z = mfma16(a0, bw[g][u][0], z);
                z = mfma16(a1, bw[g][u][1], z);
                acc[g][u] = mfma16(a2, bw[g][u][2], z);
            }
#pragma unroll
        for (int u = 0; u < 4; ++u)
#pragma unroll
            for (int r = 0; r < 4; ++r) {
                float Ei = ex2(-acc[0][u][r]);           // exp(-i)
                float Ef = ex2(-acc[1][u][r]);           // exp(-f)
                float Eg = ex2(-acc[2][u][r]);           // exp(-2g)
                float Eo = ex2(-acc[3][u][r]);           // exp(-o)
                float P = (1.f + Ei) * (1.f + Eg);
                float Q = 1.f + Ef;
                float num = fmaf(cst[u][r], P, (1.f - Eg) * Q);
                float cc = num * rcpf(P * Q);
                cst[u][r] = cc;
                float Ec = ex2(-2.f * L2E * cc);         // exp(-2c)
                float h = (1.f - Ec) * rcpf((1.f + Eo) * (1.f + Ec));
                hval[u][r] = h;
                Hs[(quad*4 + r)*HST + u*16 + lcol] = f2bf_t(h);
            }
    };

    // ---- encoder ----
    build_bw(ws + WS_WHHE);
    for (int stp = 0; stp < TT; ++stp) {
        lstm_step();
        if (stp < TT - 1) {
            int row = l >> 2, k = l & 3;
            Hs[row*HST + 64 + k] = inp[row*120 + (stp + 1)*4 + k];
        }
    }
    // hT (bf16) in Hs cols 0..63

    // ---- MLPs (wave-local) ----
    auto mlp_hidden = [&](bf16x8 a0, bf16x8 a1, const u16* wsW, const float* bg,
                          u16* outB, int ost) {
#pragma unroll
        for (int u = 0; u < 4; ++u) {
            int n = u*16 + lcol;
            const u16* wr = wsW + n*64;
            bf16x8 bb0 = *(const bf16x8*)(wr + quad*8);
            bf16x8 bb1 = *(const bf16x8*)(wr + 32 + quad*8);
            float bv = bg[n];
            f32x4 acc = {bv, bv, bv, bv};
            acc = mfma16(a0, bb0, acc);
            acc = mfma16(a1, bb1, acc);
#pragma unroll
            for (int r = 0; r < 4; ++r)
                outB[(quad*4 + r)*ost + n] = f2bf_t(leaky(acc[r]));
        }
    };

    {
        // layer 1 (reads hT once, feeds both chains; lv chain overwrites Hs in place)
        bf16x8 t0 = *(const bf16x8*)(Hs + lcol*HST + quad*8);
        bf16x8 t1 = *(const bf16x8*)(Hs + lcol*HST + 32 + quad*8);
        mlp_hidden(t0, t1, ws + WS_MWS, mean_bs, XS, 64);
        mlp_hidden(t0, t1, ws + WS_LWS, lv_bs, Hs, HST);
        // layer 2
        bf16x8 m0 = *(const bf16x8*)(XS + lcol*64 + quad*8);
        bf16x8 m1 = *(const bf16x8*)(XS + lcol*64 + 32 + quad*8);
        mlp_hidden(m0, m1, ws + WS_MWS + 4096, mean_bs + 64, XS, 64);
        bf16x8 v0 = *(const bf16x8*)(Hs + lcol*HST + quad*8);
        bf16x8 v1 = *(const bf16x8*)(Hs + lcol*HST + 32 + quad*8);
        mlp_hidden(v0, v1, ws + WS_LWS + 4096, lv_bs + 64, Hs, HST);
        // layer 3
        m0 = *(const bf16x8*)(XS + lcol*64 + quad*8);
        m1 = *(const bf16x8*)(XS + lcol*64 + 32 + quad*8);
        mlp_hidden(m0, m1, ws + WS_MWS + 8192, mean_bs + 128, XS, 64);
        v0 = *(const bf16x8*)(Hs + lcol*HST + quad*8);
        v1 = *(const bf16x8*)(Hs + lcol*HST + 32 + quad*8);
        mlp_hidden(v0, v1, ws + WS_LWS + 8192, lv_bs + 128, Hs, HST);
    }

    float muv[7][4];   // mu kept in f32 registers (statically indexed only)

    // ---- mean final: mu -> regs + out_mu ----
    {
        bf16x8 fa = *(const bf16x8*)(XS + lcol*64 + quad*8);
        bf16x8 fb = *(const bf16x8*)(XS + lcol*64 + 32 + quad*8);
#pragma unroll
        for (int nt = 0; nt < 7; ++nt) {
            int n = nt*16 + lcol;
            bool ok = (n < LL);
            bf16x8 bb0, bb1;
            if (ok) {
                const u16* wr = ws + WS_MWF + n*64;
                bb0 = *(const bf16x8*)(wr + quad*8);
                bb1 = *(const bf16x8*)(wr + 32 + quad*8);
            } else {
#pragma unroll
                for (int j = 0; j < 8; ++j) { bb0[j] = 0; bb1[j] = 0; }
            }
            float bv = ok ? mean_bf[n] : 0.f;
            f32x4 acc = {bv, bv, bv, bv};
            acc = mfma16(fa, bb0, acc);
            acc = mfma16(fb, bb1, acc);
#pragma unroll
            for (int r = 0; r < 4; ++r) {
                float vv = leaky(acc[r]);
                muv[nt][r] = vv;
                if (ok) out_mu[(size_t)(b0 + quad*4 + r) * LL + n] = vv;
            }
        }
    }

    // ---- logvar final + fused reparameterization: z -> zB ----
    {
        bf16x8 fa = *(const bf16x8*)(Hs + lcol*HST + quad*8);
        bf16x8 fb = *(const bf16x8*)(Hs + lcol*HST + 32 + quad*8);
#pragma unroll
        for (int nt = 0; nt < 7; ++nt) {
            int n = nt*16 + lcol;
            bool ok = (n < LL);
            bf16x8 bb0, bb1;
            if (ok) {
                const u16* wr = ws + WS_LWF + n*64;
                bb0 = *(const bf16x8*)(wr + quad*8);
                bb1 = *(const bf16x8*)(wr + 32 + quad*8);
            } else {
#pragma unroll
                for (int j = 0; j < 8; ++j) { bb0[j] = 0; bb1[j] = 0; }
            }
            float bv = ok ? lv_bf[n] : 0.f;
            f32x4 acc = {bv, bv, bv, bv};
            acc = mfma16(fa, bb0, acc);
            acc = mfma16(fb, bb1, acc);
#pragma unroll
            for (int r = 0; r < 4; ++r) {
                if (ok) {
                    float lv = leaky(acc[r]);
                    size_t gi = (size_t)(b0 + quad*4 + r) * LL + n;
                    out_lv[gi] = lv;
                    float zv = tanh_(fmaf(eps[gi], __expf(0.5f * lv), muv[nt][r]));
                    zB[(quad*4 + r)*136 + n] = f2bf_t(zv);
                }
            }
        }
    }

    // ---- dh = z @ W_init^T + b_init -> c-state + Hs (h0) ----
    {
        bf16x8 az[4];
#pragma unroll
        for (int kt = 0; kt < 4; ++kt)
            az[kt] = *(const bf16x8*)(zB + lcol*136 + kt*32 + quad*8);
#pragma unroll
        for (int u = 0; u < 4; ++u) {
            int n = u*16 + lcol;
            float bv = b_init[n];
            f32x4 acc = {bv, bv, bv, bv};
#pragma unroll
            for (int kt = 0; kt < 4; ++kt) {
                bf16x8 bi = *(const bf16x8*)(ws + WS_WINIT + n*128 + kt*32 + quad*8);
                acc = mfma16(az[kt], bi, acc);
            }
#pragma unroll
            for (int r = 0; r < 4; ++r) {
                cst[u][r] = acc[r];
                Hs[(quad*4 + r)*HST + n] = f2bf_t(acc[r]);
            }
        }
    }

    // ---- decoder prep ----
    {
        int row = l >> 2, k = l & 3;
        Hs[row*HST + 64 + k] = f2bf(init_state[(size_t)(b0 + row)*4 + k]);
    }
    float px = 0.f, py = 0.f, ppsi = 0.f, pv = 0.f;   // physics state (16 lanes)
    if (lcol < 4) {
        int row = quad*4 + lcol;
        const float* is = init_state + (size_t)(b0 + row)*4;
        px = is[0]; py = is[1]; ppsi = is[2]; pv = is[3];
    }
    float wc0[4], wc1[4];
#pragma unroll
    for (int u = 0; u < 4; ++u) {
        wc0[u] = W_c[u*16 + lcol];
        wc1[u] = W_c[64 + u*16 + lcol];
    }
    const float bc0 = b_c[0], bc1 = b_c[1];
    build_bw(ws + WS_WHHD);

    // ---- decoder ----
    for (int stp = 0; stp < TT; ++stp) {
        lstm_step();     // hval = f32 h (closer to reference than bf16 round-trip)
        // ctrl = h @ W_c^T : per-lane partials over own 4 unit-blocks, then
        // 16-lane (intra-quad-group) shuffle reduce
        float pa[4], pb[4];
#pragma unroll
        for (int r = 0; r < 4; ++r) {
            float s0 = 0.f, s1 = 0.f;
#pragma unroll
            for (int u = 0; u < 4; ++u) {
                s0 = fmaf(hval[u][r], wc0[u], s0);
                s1 = fmaf(hval[u][r], wc1[u], s1);
            }
            pa[r] = s0; pb[r] = s1;
        }
#pragma unroll
        for (int d = 1; d < 16; d <<= 1) {
#pragma unroll
            for (int r = 0; r < 4; ++r) {
                pa[r] += __shfl_xor(pa[r], d);
                pb[r] += __shfl_xor(pb[r], d);
            }
        }
        if (lcol < 4) {  // lane (quad, lcol) owns row quad*4+lcol
            float a0s = lcol == 0 ? pa[0] : lcol == 1 ? pa[1] : lcol == 2 ? pa[2] : pa[3];
            float a1s = lcol == 0 ? pb[0] : lcol == 1 ? pb[1] : lcol == 2 ? pb[2] : pb[3];
            float pedal = a0s + bc0;
            float steer = fminf(fmaxf(a1s + bc1, -0.5f), 0.5f);
            float v1 = fminf(fmaxf(pv + pedal * DTC, 0.f), 30.f);
            float sn, cs;
            __sincosf(ppsi, &sn, &cs);
            float psid = fminf(fmaxf(pv * __tanf(steer) * 0.4f, -1.57f), 1.57f);
            float nx = fmaf(pv * cs, DTC, px);
            float ny = fmaf(pv * sn, DTC, py);
            float npsi = fmaf(psid, DTC, ppsi);
            px = nx; py = ny; ppsi = npsi; pv = v1;
            int row = quad*4 + lcol;
            float4 o; o.x = nx; o.y = ny; o.z = npsi; o.w = v1;
            *(float4*)(out_recons + ((size_t)(b0 + row) * TT + stp) * 4) = o;
            u32 lo = (u32)f2bf(nx) | ((u32)f2bf(ny) << 16);
            u32 hi = (u32)f2bf(npsi) | ((u32)f2bf(v1) << 16);
            uint2 pk; pk.x = lo; pk.y = hi;
            *(uint2*)(Hs + row*HST + 64) = pk;
        }
    }
}

extern "C" void kernel_launch(void* const* d_in, const int* in_sizes, int n_in,
                              void* d_out, int out_size, void* d_ws, size_t ws_size,
                              hipStream_t stream) {
    (void)in_sizes; (void)n_in; (void)ws_size; (void)out_size;
    const float* expert    = (const float*)d_in[0];
    const float* init_st   = (const float*)d_in[1];
    const float* eps       = (const float*)d_in[2];
    const float* W_se      = (const float*)d_in[3];
    const float* b_se      = (const float*)d_in[4];
    const float* W_ih_e    = (const float*)d_in[5];
    const float* W_hh_e    = (const float*)d_in[6];
    const float* b_ih_e    = (const float*)d_in[7];
    const float* b_hh_e    = (const float*)d_in[8];
    const float* mean_Ws   = (const float*)d_in[9];
    const float* mean_bs   = (const float*)d_in[10];
    const float* mean_Wf   = (const float*)d_in[11];
    const float* mean_bf   = (const float*)d_in[12];
    const float* lv_Ws     = (const float*)d_in[13];
    const float* lv_bs     = (const float*)d_in[14];
    const float* lv_Wf     = (const float*)d_in[15];
    const float* lv_bf     = (const float*)d_in[16];
    const float* W_init    = (const float*)d_in[17];
    const float* b_init    = (const float*)d_in[18];
    const float* W_ih_d    = (const float*)d_in[19];
    const float* W_hh_d    = (const float*)d_in[20];
    const float* b_ih_d    = (const float*)d_in[21];
    const float* b_hh_d    = (const float*)d_in[22];
    const float* W_c       = (const float*)d_in[23];
    const float* b_c       = (const float*)d_in[24];

    float* out = (float*)d_out;
    const size_t n_traj = (size_t)B_TOT * TT * 4;
    const size_t n_lat  = (size_t)B_TOT * LL;
    float* out_recons = out;
    float* out_expert = out + n_traj;
    float* out_mu     = out + 2 * n_traj;
    float* out_lv     = out + 2 * n_traj + n_lat;

    u16* ws = (u16*)d_ws;

    setup_kernel<<<64, 256, 0, stream>>>(
        W_se, b_se, W_ih_e, W_hh_e, b_ih_e, b_hh_e,
        W_ih_d, W_hh_d, b_ih_d, b_hh_d,
        mean_Ws, lv_Ws, mean_Wf, lv_Wf, W_init, ws);

    vae_lstm_kernel<<<NBLK, BLK, 0, stream>>>(
        expert, init_st, eps, ws,
        mean_bs, mean_bf, lv_bs, lv_bf, b_init, W_c, b_c,
        out_recons, out_expert, out_mu, out_lv);
}

// Round 5
// 227.898 us; speedup vs baseline: 1.0980x; 1.0980x over previous
//
#include <hip/hip_runtime.h>

typedef unsigned short u16;
typedef unsigned int u32;
typedef __attribute__((ext_vector_type(8))) short bf16x8;
typedef __attribute__((ext_vector_type(4))) float f32x4;

#define B_TOT 16384
#define RR 16                // batch rows per block
#define BLK 128              // 2 waves: wave w owns hidden units [w*32, w*32+32)
#define NBLK (B_TOT / RR)    // 1024 blocks -> 4 blocks/CU, 8 waves/CU (2/SIMD)
#define TT 30
#define LL 100
#define DTC 0.03f
#define L2E 1.44269504088896f

#define HST 104              // u16 stride of H rows (h 0..63, x 64..67, bias 68, pad)
#define HBUF (RR * HST)      // 1664 u16 per buffer

// ---- LDS byte offsets, total 18944 ----
#define OFF_H   0            // u16[2][16][104] = 6656 : double-buffered LSTM state
#define OFF_XS  6656         // u16[2][16][64]  = 4096 : MLP ping-pong; f32 ctrl scratch alias
#define OFF_INP 10752        // u16[16][120]    = 3840 : encoder inputs (bf16)
#define OFF_ZB  14592        // u16[16][136]    = 4352 : z, zero-padded to K=128
#define SMEM_SZ 18944

// ---- d_ws u16 offsets (unchanged, proven) ----
#define WS_WHHE  0        // [256][72]: cols0-63 whh*scale, 64-67 fold, 68 bias, 69-71 zero
#define WS_WHHD  18432
#define WS_MWS   36864    // mean_Ws 3x[64][64]
#define WS_LWS   49152
#define WS_MWF   61440    // [100][64]
#define WS_LWF   67840
#define WS_WINIT 74240    // [64][128] zero-padded
#define WS_TOTAL 82432

__device__ __forceinline__ float bf2f(u16 u) {
    union { u32 i; float f; } v; v.i = ((u32)u) << 16; return v.f;
}
__device__ __forceinline__ u16 f2bf(float f) {          // RNE (setup / one-shot paths)
    union { float f; u32 i; } v; v.f = f;
    return (u16)((v.i + 0x7FFFu + ((v.i >> 16) & 1u)) >> 16);
}
__device__ __forceinline__ u16 f2bf_t(float f) {        // truncation (hot paths)
    union { float f; u32 i; } v; v.f = f;
    return (u16)(v.i >> 16);
}
__device__ __forceinline__ float rcpf(float x) { return __builtin_amdgcn_rcpf(x); }
__device__ __forceinline__ float ex2(float x) { return __builtin_amdgcn_exp2f(x); }
__device__ __forceinline__ float tanh_(float x) {
    x = fminf(fmaxf(x, -15.f), 15.f);
    float e = __expf(2.f * x);
    return (e - 1.f) * rcpf(e + 1.f);
}
__device__ __forceinline__ float leaky(float x) { return x >= 0.f ? x : 0.01f * x; }
__device__ __forceinline__ f32x4 mfma16(bf16x8 a, bf16x8 b, f32x4 c) {
    return __builtin_amdgcn_mfma_f32_16x16x32_bf16(a, b, c, 0, 0, 0);
}

// ================= setup kernel: weight prep into d_ws (unchanged) =================
__global__ void setup_kernel(
    const float* __restrict__ W_se, const float* __restrict__ b_se,
    const float* __restrict__ W_ih_e, const float* __restrict__ W_hh_e,
    const float* __restrict__ b_ih_e, const float* __restrict__ b_hh_e,
    const float* __restrict__ W_ih_d, const float* __restrict__ W_hh_d,
    const float* __restrict__ b_ih_d, const float* __restrict__ b_hh_d,
    const float* __restrict__ mean_Ws, const float* __restrict__ lv_Ws,
    const float* __restrict__ mean_Wf, const float* __restrict__ lv_Wf,
    const float* __restrict__ W_init, u16* __restrict__ ws)
{
    const int gid = blockIdx.x * 256 + threadIdx.x;
    const int nth = gridDim.x * 256;
    // A: folded input-proj tails (512 dot-tasks)
    for (int i = gid; i < 512; i += nth) {
        int which = i >> 8, row = i & 255, g = row >> 6;
        float s = (g == 2) ? 2.f * L2E : L2E;
        const float* wih = (which ? W_ih_d : W_ih_e) + row * 64;
        float f0=0,f1=0,f2=0,f3=0,fb=0;
        for (int e = 0; e < 64; ++e) {
            float w = wih[e];
            f0 = fmaf(w, W_se[e*4+0], f0);
            f1 = fmaf(w, W_se[e*4+1], f1);
            f2 = fmaf(w, W_se[e*4+2], f2);
            f3 = fmaf(w, W_se[e*4+3], f3);
            fb = fmaf(w, b_se[e], fb);
        }
        fb += (which ? b_ih_d : b_ih_e)[row] + (which ? b_hh_d : b_hh_e)[row];
        u16* dst = ws + (which ? WS_WHHD : WS_WHHE) + row * 72 + 64;
        dst[0]=f2bf(f0*s); dst[1]=f2bf(f1*s); dst[2]=f2bf(f2*s); dst[3]=f2bf(f3*s);
        dst[4]=f2bf(fb*s); dst[5]=0; dst[6]=0; dst[7]=0;
    }
    // B: scaled W_hh rows
    for (int i = gid; i < 2*16384; i += nth) {
        int which = i >= 16384;
        int j = which ? i - 16384 : i;
        int row = j >> 6, k = j & 63, g = row >> 6;
        float s = (g == 2) ? 2.f * L2E : L2E;
        const float* whh = which ? W_hh_d : W_hh_e;
        ws[(which ? WS_WHHD : WS_WHHE) + row*72 + k] = f2bf(whh[j] * s);
    }
    // C: MLP hidden weights
    for (int i = gid; i < 12288; i += nth) {
        ws[WS_MWS + i] = f2bf(mean_Ws[i]);
        ws[WS_LWS + i] = f2bf(lv_Ws[i]);
    }
    // D: MLP final weights
    for (int i = gid; i < 6400; i += nth) {
        ws[WS_MWF + i] = f2bf(mean_Wf[i]);
        ws[WS_LWF + i] = f2bf(lv_Wf[i]);
    }
    // E: W_init zero-padded [64][128]
    for (int i = gid; i < 8192; i += nth) {
        int r = i >> 7, k = i & 127;
        ws[WS_WINIT + i] = (k < LL) ? f2bf(W_init[r*LL + k]) : (u16)0;
    }
}

// ================= main fused kernel: 2 waves, unit-split =================
// Wave w owns hidden units [w*32, w*32+32): B-frags = 4 gates x 2 u-blocks x 3 k = 24
// frags = 96 VGPRs -> resident under the 256-reg budget (launch_bounds(128,2)).
// Full 16-row MFMA tiles. Double-buffered H + 1 barrier/step (encoder),
// 2/step (decoder, for the ctrl-partial exchange). 2 waves/SIMD for latency hiding.
__global__ __launch_bounds__(BLK, 2) void vae_lstm_kernel(
    const float* __restrict__ expert, const float* __restrict__ init_state,
    const float* __restrict__ eps, const u16* __restrict__ ws,
    const float* __restrict__ mean_bs, const float* __restrict__ mean_bf,
    const float* __restrict__ lv_bs, const float* __restrict__ lv_bf,
    const float* __restrict__ b_init, const float* __restrict__ W_c,
    const float* __restrict__ b_c,
    float* __restrict__ out_recons, float* __restrict__ out_expert,
    float* __restrict__ out_mu, float* __restrict__ out_lv)
{
    const int tid = threadIdx.x;
    const int wv = tid >> 6;          // 0/1: unit-half owner
    const int l = tid & 63;
    const int lcol = l & 15;
    const int quad = l >> 4;
    const int ubase = wv * 32;
    const int b0 = blockIdx.x * RR;

    __shared__ __align__(16) char smem[SMEM_SZ];
    u16* Hb  = (u16*)(smem + OFF_H);      // Hb + (p)*HBUF : buffer p
    u16* XS  = (u16*)(smem + OFF_XS);
    u16* XA  = XS;                         // MLP ping
    u16* XB  = XS + RR*64;                 // MLP pong
    u16* inp = (u16*)(smem + OFF_INP);
    u16* zB  = (u16*)(smem + OFF_ZB);
    float* sc = (float*)XS;                // decoder ctrl scratch (64 f32), XS dead then

    // ---- staging ----
    {
        u32* hz = (u32*)Hb;
        for (int idx = tid; idx < 2*RR*52; idx += BLK) hz[idx] = 0;   // both H buffers
        u32* zz = (u32*)zB;
        for (int idx = tid; idx < RR*68; idx += BLK) zz[idx] = 0;     // zB incl pad
        __syncthreads();
        if (tid < 32) Hb[(tid >> 4)*HBUF + (tid & 15)*HST + 68] = 0x3F80;  // bias = 1.0
        const int base = b0 * (TT*4);
        for (int idx = tid; idx < RR*TT*4; idx += BLK) {
            int row = idx / 120, q = idx % 120;
            int t = q >> 2, k = q & 3;
            float v = expert[base + idx];
            out_expert[base + idx] = v;
            float r = v;
            if (k < 2 && t > 0) r = v - expert[base + idx - 4];
            u16 hv = f2bf(r);
            inp[row*120 + q] = hv;
            if (t == 0) Hb[row*HST + 64 + k] = hv;    // x(t=0) -> buffer 0
        }
        __syncthreads();
    }

    float cst[2][4] = {};      // c-state: [unit-block ul][row-reg r]
    float hval[2][4];          // f32 h of current step (decoder ctrl input)
    bf16x8 bw[4][2][3];        // B-frags: [gate g][unit-block ul][k-block] = 96 VGPRs

    auto build_bw = [&](const u16* wsW) {
#pragma unroll
        for (int g = 0; g < 4; ++g)
#pragma unroll
            for (int ul = 0; ul < 2; ++ul) {
                const u16* wr = wsW + (g*64 + ubase + ul*16 + lcol) * 72;
                bw[g][ul][0] = *(const bf16x8*)(wr + quad*8);
                bw[g][ul][1] = *(const bf16x8*)(wr + 32 + quad*8);
                if (quad == 0) {
                    bw[g][ul][2] = *(const bf16x8*)(wr + 64);
                } else {
                    bf16x8 z;
#pragma unroll
                    for (int j = 0; j < 8; ++j) z[j] = 0;
                    bw[g][ul][2] = z;
                }
            }
    };

    // one LSTM step: 24 MFMA (K=96, 16 full rows) + fused gate epilogue for 32 units
    auto lstm_step = [&](const u16* Hc, u16* Hn) {
        const u16* hrow = Hc + lcol*HST;
        bf16x8 a0 = *(const bf16x8*)(hrow + quad*8);
        bf16x8 a1 = *(const bf16x8*)(hrow + 32 + quad*8);
        bf16x8 a2 = *(const bf16x8*)(hrow + 64 + quad*8);
        f32x4 acc[4][2];
#pragma unroll
        for (int g = 0; g < 4; ++g)
#pragma unroll
            for (int ul = 0; ul < 2; ++ul) {
                f32x4 z = {0.f, 0.f, 0.f, 0.f};
                z = mfma16(a0, bw[g][ul][0], z);
                z = mfma16(a1, bw[g][ul][1], z);
                acc[g][ul] = mfma16(a2, bw[g][ul][2], z);
            }
#pragma unroll
        for (int ul = 0; ul < 2; ++ul)
#pragma unroll
            for (int r = 0; r < 4; ++r) {
                float Ei = ex2(-acc[0][ul][r]);          // exp(-i)
                float Ef = ex2(-acc[1][ul][r]);          // exp(-f)
                float Eg = ex2(-acc[2][ul][r]);          // exp(-2g)
                float Eo = ex2(-acc[3][ul][r]);          // exp(-o)
                float P = (1.f + Ei) * (1.f + Eg);
                float Q = 1.f + Ef;
                float num = fmaf(cst[ul][r], P, (1.f - Eg) * Q);
                float cc = num * rcpf(P * Q);
                cst[ul][r] = cc;
                float Ec = ex2(-2.f * L2E * cc);         // exp(-2c)
                float h = (1.f - Ec) * rcpf((1.f + Eo) * (1.f + Ec));
                hval[ul][r] = h;
                Hn[(quad*4 + r)*HST + ubase + ul*16 + lcol] = f2bf_t(h);
            }
    };

    // ---- encoder: 1 barrier/step (double buffer kills the WAR hazard) ----
    build_bw(ws + WS_WHHE);
    for (int stp = 0; stp < TT; ++stp) {
        const u16* Hc = Hb + (stp & 1) * HBUF;
        u16* Hn = Hb + ((stp + 1) & 1) * HBUF;
        lstm_step(Hc, Hn);
        if (wv == 0 && stp < TT - 1) {
            int row = l >> 2, k = l & 3;
            Hn[row*HST + 64 + k] = inp[row*120 + (stp + 1)*4 + k];
        }
        __syncthreads();
    }
    // hT in buffer 0 (TT even)
    u16* H0 = Hb;
    u16* H1 = Hb + HBUF;

    // ---- MLP hidden layer: each wave produces its 32 output units ----
    auto mlp_hidden = [&](const u16* inB, int ist, u16* outB, int ost,
                          const u16* wsW, const float* bg) {
        bf16x8 a0 = *(const bf16x8*)(inB + lcol*ist + quad*8);
        bf16x8 a1 = *(const bf16x8*)(inB + lcol*ist + 32 + quad*8);
#pragma unroll
        for (int ul = 0; ul < 2; ++ul) {
            int n = ubase + ul*16 + lcol;
            const u16* wr = wsW + n*64;
            bf16x8 bb0 = *(const bf16x8*)(wr + quad*8);
            bf16x8 bb1 = *(const bf16x8*)(wr + 32 + quad*8);
            float bv = bg[n];
            f32x4 acc = {bv, bv, bv, bv};
            acc = mfma16(a0, bb0, acc);
            acc = mfma16(a1, bb1, acc);
#pragma unroll
            for (int r = 0; r < 4; ++r)
                outB[(quad*4 + r)*ost + n] = f2bf_t(leaky(acc[r]));
        }
        __syncthreads();
    };

    // mean chain (XS ping-pong; hT in H0 stays intact)
    mlp_hidden(H0, HST, XA, 64, ws + WS_MWS,        mean_bs);
    mlp_hidden(XA, 64,  XB, 64, ws + WS_MWS + 4096, mean_bs + 64);
    mlp_hidden(XB, 64,  XA, 64, ws + WS_MWS + 8192, mean_bs + 128);

    float muv[4][4];   // this wave's mu tiles (nt = wv, wv+2, wv+4, wv+6)

    // ---- mean final: 7 n-tiles split across waves ----
    {
        bf16x8 fa = *(const bf16x8*)(XA + lcol*64 + quad*8);
        bf16x8 fb = *(const bf16x8*)(XA + lcol*64 + 32 + quad*8);
#pragma unroll
        for (int ti = 0; ti < 4; ++ti) {
            int nt = wv + ti*2;
            if (nt > 6) continue;                  // wave1 ti=3 idle (uniform branch)
            int n = nt*16 + lcol;
            bool ok = (n < LL);
            bf16x8 bb0, bb1;
            if (ok) {
                const u16* wr = ws + WS_MWF + n*64;
                bb0 = *(const bf16x8*)(wr + quad*8);
                bb1 = *(const bf16x8*)(wr + 32 + quad*8);
            } else {
#pragma unroll
                for (int j = 0; j < 8; ++j) { bb0[j] = 0; bb1[j] = 0; }
            }
            float bv = ok ? mean_bf[n] : 0.f;
            f32x4 acc = {bv, bv, bv, bv};
            acc = mfma16(fa, bb0, acc);
            acc = mfma16(fb, bb1, acc);
#pragma unroll
            for (int r = 0; r < 4; ++r) {
                float vv = leaky(acc[r]);
                muv[ti][r] = vv;
                if (ok) out_mu[(size_t)(b0 + quad*4 + r) * LL + n] = vv;
            }
        }
    }

    // logvar chain (ping-pong between the two H buffers, cols 0-63)
    mlp_hidden(H0, HST, H1, HST, ws + WS_LWS,        lv_bs);
    mlp_hidden(H1, HST, H0, HST, ws + WS_LWS + 4096, lv_bs + 64);
    mlp_hidden(H0, HST, H1, HST, ws + WS_LWS + 8192, lv_bs + 128);

    // ---- logvar final + fused reparameterization: z -> zB ----
    {
        bf16x8 fa = *(const bf16x8*)(H1 + lcol*HST + quad*8);
        bf16x8 fb = *(const bf16x8*)(H1 + lcol*HST + 32 + quad*8);
#pragma unroll
        for (int ti = 0; ti < 4; ++ti) {
            int nt = wv + ti*2;
            if (nt > 6) continue;
            int n = nt*16 + lcol;
            bool ok = (n < LL);
            bf16x8 bb0, bb1;
            if (ok) {
                const u16* wr = ws + WS_LWF + n*64;
                bb0 = *(const bf16x8*)(wr + quad*8);
                bb1 = *(const bf16x8*)(wr + 32 + quad*8);
            } else {
#pragma unroll
                for (int j = 0; j < 8; ++j) { bb0[j] = 0; bb1[j] = 0; }
            }
            float bv = ok ? lv_bf[n] : 0.f;
            f32x4 acc = {bv, bv, bv, bv};
            acc = mfma16(fa, bb0, acc);
            acc = mfma16(fb, bb1, acc);
#pragma unroll
            for (int r = 0; r < 4; ++r) {
                if (ok) {
                    float lv = leaky(acc[r]);
                    size_t gi = (size_t)(b0 + quad*4 + r) * LL + n;
                    out_lv[gi] = lv;
                    float zv = tanh_(fmaf(eps[gi], __expf(0.5f * lv), muv[ti][r]));
                    zB[(quad*4 + r)*136 + n] = f2bf_t(zv);
                }
            }
        }
        __syncthreads();   // zB complete before dh reads all rows
    }

    // ---- dh = z @ W_init^T + b_init -> c-state + H0 (h0, own unit-cols) ----
    {
        bf16x8 az[4];
#pragma unroll
        for (int kt = 0; kt < 4; ++kt)
            az[kt] = *(const bf16x8*)(zB + lcol*136 + kt*32 + quad*8);
#pragma unroll
        for (int ul = 0; ul < 2; ++ul) {
            int n = ubase + ul*16 + lcol;
            float bv = b_init[n];
            f32x4 acc = {bv, bv, bv, bv};
#pragma unroll
            for (int kt = 0; kt < 4; ++kt) {
                bf16x8 bi = *(const bf16x8*)(ws + WS_WINIT + n*128 + kt*32 + quad*8);
                acc = mfma16(az[kt], bi, acc);
            }
#pragma unroll
            for (int r = 0; r < 4; ++r) {
                cst[ul][r] = acc[r];
                H0[(quad*4 + r)*HST + n] = f2bf_t(acc[r]);
            }
        }
    }

    // ---- decoder prep ----
    if (wv == 0) {
        int row = l >> 2, k = l & 3;
        H0[row*HST + 64 + k] = f2bf(init_state[(size_t)(b0 + row)*4 + k]);
    }
    float px = 0.f, py = 0.f, ppsi = 0.f, pv = 0.f;   // physics (wave0 lanes 0-15)
    if (tid < 16) {
        const float* is = init_state + (size_t)(b0 + tid)*4;
        px = is[0]; py = is[1]; ppsi = is[2]; pv = is[3];
    }
    float wc0[2], wc1[2];
#pragma unroll
    for (int ul = 0; ul < 2; ++ul) {
        wc0[ul] = W_c[ubase + ul*16 + lcol];
        wc1[ul] = W_c[64 + ubase + ul*16 + lcol];
    }
    const float bc0 = b_c[0], bc1 = b_c[1];
    build_bw(ws + WS_WHHD);
    __syncthreads();

    // ---- decoder: 2 barriers/step (h-exchange + ctrl-partial exchange) ----
    for (int stp = 0; stp < TT; ++stp) {
        const u16* Hc = Hb + (stp & 1) * HBUF;
        u16* Hn = Hb + ((stp + 1) & 1) * HBUF;
        lstm_step(Hc, Hn);
        // ctrl partial over own 32 units, reduce across the 16 lcol lanes
        float pa[4], pb[4];
#pragma unroll
        for (int r = 0; r < 4; ++r) {
            pa[r] = fmaf(hval[0][r], wc0[0], hval[1][r] * wc0[1]);
            pb[r] = fmaf(hval[0][r], wc1[0], hval[1][r] * wc1[1]);
        }
#pragma unroll
        for (int d = 1; d < 16; d <<= 1) {
#pragma unroll
            for (int r = 0; r < 4; ++r) {
                pa[r] += __shfl_xor(pa[r], d);
                pb[r] += __shfl_xor(pb[r], d);
            }
        }
        if (lcol == 0) {
#pragma unroll
            for (int r = 0; r < 4; ++r) {
                sc[wv*32 + quad*4 + r]      = pa[r];
                sc[wv*32 + 16 + quad*4 + r] = pb[r];
            }
        }
        __syncthreads();
        if (tid < 16) {
            int row = tid;
            float pedal = sc[row] + sc[32 + row] + bc0;
            float steer = fminf(fmaxf(sc[16 + row] + sc[48 + row] + bc1, -0.5f), 0.5f);
            float v1 = fminf(fmaxf(pv + pedal * DTC, 0.f), 30.f);
            float sn, cs;
            __sincosf(ppsi, &sn, &cs);
            float psid = fminf(fmaxf(pv * __tanf(steer) * 0.4f, -1.57f), 1.57f);
            float nx = fmaf(pv * cs, DTC, px);
            float ny = fmaf(pv * sn, DTC, py);
            float npsi = fmaf(psid, DTC, ppsi);
            px = nx; py = ny; ppsi = npsi; pv = v1;
            float4 o; o.x = nx; o.y = ny; o.z = npsi; o.w = v1;
            *(float4*)(out_recons + ((size_t)(b0 + row) * TT + stp) * 4) = o;
            u32 lo = (u32)f2bf(nx) | ((u32)f2bf(ny) << 16);
            u32 hi = (u32)f2bf(npsi) | ((u32)f2bf(v1) << 16);
            uint2 pk; pk.x = lo; pk.y = hi;
            *(uint2*)(Hn + row*HST + 64) = pk;
        }
        __syncthreads();
    }
}

extern "C" void kernel_launch(void* const* d_in, const int* in_sizes, int n_in,
                              void* d_out, int out_size, void* d_ws, size_t ws_size,
                              hipStream_t stream) {
    (void)in_sizes; (void)n_in; (void)ws_size; (void)out_size;
    const float* expert    = (const float*)d_in[0];
    const float* init_st   = (const float*)d_in[1];
    const float* eps       = (const float*)d_in[2];
    const float* W_se      = (const float*)d_in[3];
    const float* b_se      = (const float*)d_in[4];
    const float* W_ih_e    = (const float*)d_in[5];
    const float* W_hh_e    = (const float*)d_in[6];
    const float* b_ih_e    = (const float*)d_in[7];
    const float* b_hh_e    = (const float*)d_in[8];
    const float* mean_Ws   = (const float*)d_in[9];
    const float* mean_bs   = (const float*)d_in[10];
    const float* mean_Wf   = (const float*)d_in[11];
    const float* mean_bf   = (const float*)d_in[12];
    const float* lv_Ws     = (const float*)d_in[13];
    const float* lv_bs     = (const float*)d_in[14];
    const float* lv_Wf     = (const float*)d_in[15];
    const float* lv_bf     = (const float*)d_in[16];
    const float* W_init    = (const float*)d_in[17];
    const float* b_init    = (const float*)d_in[18];
    const float* W_ih_d    = (const float*)d_in[19];
    const float* W_hh_d    = (const float*)d_in[20];
    const float* b_ih_d    = (const float*)d_in[21];
    const float* b_hh_d    = (const float*)d_in[22];
    const float* W_c       = (const float*)d_in[23];
    const float* b_c       = (const float*)d_in[24];

    float* out = (float*)d_out;
    const size_t n_traj = (size_t)B_TOT * TT * 4;
    const size_t n_lat  = (size_t)B_TOT * LL;
    float* out_recons = out;
    float* out_expert = out + n_traj;
    float* out_mu     = out + 2 * n_traj;
    float* out_lv     = out + 2 * n_traj + n_lat;

    u16* ws = (u16*)d_ws;

    setup_kernel<<<64, 256, 0, stream>>>(
        W_se, b_se, W_ih_e, W_hh_e, b_ih_e, b_hh_e,
        W_ih_d, W_hh_d, b_ih_d, b_hh_d,
        mean_Ws, lv_Ws, mean_Wf, lv_Wf, W_init, ws);

    vae_lstm_kernel<<<NBLK, BLK, 0, stream>>>(
        expert, init_st, eps, ws,
        mean_bs, mean_bf, lv_bs, lv_bf, b_init, W_c, b_c,
        out_recons, out_expert, out_mu, out_lv);
}